// Round 5
// baseline (114.993 us; speedup 1.0000x reference)
//
#include <hip/hip_runtime.h>

// CurvatureLoss: B=4, N=4096, fp32.
// R5: R4 was co-limited by L2 candidate traffic (1 GB: 8192 waves x 128 KB)
// and VALU issue (~20 us floor). QPW 2 -> 4: same 2 loads/step now feed
// 12 keys -> L2 traffic halves (512 MB), wave count 4096 = 4 waves/SIMD.
//  - keys: q.c - 0.5|c|^2 packed as float4 w; larger = closer.
//  - 6-bit step index embedded in mantissa -> pure min/max top-2, index
//    recovered post-merge via __ballot (lowest lane = smallest j).
//  - butterfly __shfl_xor top2 merge; per-block partial + reduce kernel.

constexpr int BB   = 4;
constexpr int NN   = 4096;
constexpr int QPW  = 4;               // queries per wave
constexpr int WPB  = 4;               // waves per block
constexpr int QPB  = QPW * WPB;       // 16 queries per block
constexpr int CPB  = 64;              // chunk = lane
constexpr int NK   = NN / CPB;        // 64 steps; candidate j = 64*k + lane
constexpr int NBLK = BB * NN / QPB;   // 1024 blocks
constexpr float NEGBIG = -3.402823466e+38f;

__global__ __launch_bounds__(256) void pack_kernel(
    const float* __restrict__ ori, const float* __restrict__ adv,
    float4* __restrict__ oriP, float4* __restrict__ advP)
{
    const int i = blockIdx.x * blockDim.x + threadIdx.x;
    if (i < BB * NN) {
        float x = ori[3 * i], y = ori[3 * i + 1], z = ori[3 * i + 2];
        oriP[i] = make_float4(x, y, z, 0.5f * (x * x + y * y + z * z));
        x = adv[3 * i]; y = adv[3 * i + 1]; z = adv[3 * i + 2];
        advP[i] = make_float4(x, y, z, 0.5f * (x * x + y * y + z * z));
    }
}

__device__ __forceinline__ float embed6(float t, unsigned eb) {
    return __uint_as_float((__float_as_uint(t) & 0xFFFFFFC0u) | eb);
}

// v: merged key; p0/p1: this lane's saved partials. All lanes execute;
// result wave-uniform. Lowest matching lane = smallest global index.
__device__ __forceinline__ int recover_j(float v, float p0, float p1) {
    unsigned long long m = __ballot((p0 == v) || (p1 == v));
    const int lane = (int)__ffsll(m) - 1;
    const int k = (NK - 1) - (int)(__float_as_uint(v) & (unsigned)(NK - 1));
    return (k << 6) | lane;
}

__device__ __forceinline__ float unit_absdot4(const float4* __restrict__ pc, int i,
                                              float px, float py, float pz,
                                              float nx, float ny, float nz) {
    const float4 c = pc[i];
    const float vx = c.x - px, vy = c.y - py, vz = c.z - pz;
    const float s  = vx * vx + vy * vy + vz * vz + 1e-12f;
    return fabsf((vx * nx + vy * ny + vz * nz) * (1.0f / sqrtf(s)));
}

__global__ __launch_bounds__(256) void knn_kernel(
    const float4* __restrict__ oriP, const float4* __restrict__ advP,
    const float* __restrict__ nrm, float* __restrict__ partial,
    float* __restrict__ out, int use_partial)
{
    const int tid = threadIdx.x;
    const int ch  = tid & 63;          // chunk = lane
    const int qs  = tid >> 6;          // wave id 0..3
    const int b   = blockIdx.x >> 8;   // 256 blocks per batch
    const int qt  = blockIdx.x & 255;
    const int q0  = qt * QPB + qs * QPW;   // queries q0..q0+3

    const float4* __restrict__ ob = oriP + (size_t)b * NN;
    const float4* __restrict__ ab = advP + (size_t)b * NN;
    const float*  __restrict__ nb = nrm  + (size_t)b * NN * 3;

    float4 qo[QPW], qa[QPW];
    int    ks[QPW];                    // self step (or NK) for this lane
    #pragma unroll
    for (int i = 0; i < QPW; ++i) {
        qo[i] = ob[q0 + i];
        qa[i] = ab[q0 + i];
        ks[i] = (((q0 + i) & 63) == ch) ? ((q0 + i) >> 6) : NK;
    }

    float oA[QPW], oB[QPW], aA[QPW], aB[QPW], mm[QPW];
    #pragma unroll
    for (int i = 0; i < QPW; ++i) {
        oA[i] = oB[i] = aA[i] = aB[i] = mm[i] = NEGBIG;
    }

    const float4* __restrict__ op = ob + ch;
    const float4* __restrict__ ap = ab + ch;

    #pragma unroll 4
    for (int k = 0; k < NK; ++k) {
        const float4 co = op[k * CPB];
        const float4 ca = ap[k * CPB];
        const unsigned eb = (unsigned)(NK - 1 - k);  // smaller index -> larger key

        #pragma unroll
        for (int i = 0; i < QPW; ++i) {
            float t;
            t = fmaf(qo[i].z, co.z, -co.w); t = fmaf(qo[i].y, co.y, t); t = fmaf(qo[i].x, co.x, t);
            float ko = embed6(t, eb);                      // ori-ori
            t = fmaf(qa[i].z, co.z, -co.w); t = fmaf(qa[i].y, co.y, t); t = fmaf(qa[i].x, co.x, t);
            const float km = embed6(t, eb);                // adv->ori (no excl.)
            t = fmaf(qa[i].z, ca.z, -ca.w); t = fmaf(qa[i].y, ca.y, t); t = fmaf(qa[i].x, ca.x, t);
            float ka = embed6(t, eb);                      // adv-adv

            if (k == ks[i]) { ko = NEGBIG; ka = NEGBIG; }  // self exclusion

            oB[i] = fmaxf(oB[i], fminf(oA[i], ko)); oA[i] = fmaxf(oA[i], ko);
            aB[i] = fmaxf(aB[i], fminf(aA[i], ka)); aA[i] = fmaxf(aA[i], ka);
            mm[i] = fmaxf(mm[i], km);
        }
    }

    // save per-lane partials for index recovery
    float soA[QPW], soB[QPW], saA[QPW], saB[QPW], sm[QPW];
    #pragma unroll
    for (int i = 0; i < QPW; ++i) {
        soA[i] = oA[i]; soB[i] = oB[i];
        saA[i] = aA[i]; saB[i] = aB[i];
        sm[i]  = mm[i];
    }

    // wave butterfly top2-merge: m0=max(a0,b0); m1=max(min(a0,b0),max(a1,b1))
    #pragma unroll
    for (int off = 1; off < 64; off <<= 1) {
        #pragma unroll
        for (int i = 0; i < QPW; ++i) {
            float r0, r1, mn;
            r0 = __shfl_xor(oA[i], off); r1 = __shfl_xor(oB[i], off);
            mn = fminf(oA[i], r0); oA[i] = fmaxf(oA[i], r0);
            oB[i] = fmaxf(mn, fmaxf(oB[i], r1));
            r0 = __shfl_xor(aA[i], off); r1 = __shfl_xor(aB[i], off);
            mn = fminf(aA[i], r0); aA[i] = fmaxf(aA[i], r0);
            aB[i] = fmaxf(mn, fmaxf(aB[i], r1));
            mm[i] = fmaxf(mm[i], __shfl_xor(mm[i], off));
        }
    }

    // recover global candidate indices (wave-uniform; all lanes participate)
    int jo0[QPW], jo1[QPW], ja0[QPW], ja1[QPW], jm[QPW];
    #pragma unroll
    for (int i = 0; i < QPW; ++i) {
        jo0[i] = recover_j(oA[i], soA[i], soB[i]);
        jo1[i] = recover_j(oB[i], soA[i], soB[i]);
        ja0[i] = recover_j(aA[i], saA[i], saB[i]);
        ja1[i] = recover_j(aB[i], saA[i], saB[i]);
        jm[i]  = recover_j(mm[i], sm[i], sm[i]);
    }

    // epilogue: lane 0 of each wave computes all 4 queries (constant indices)
    float val = 0.0f;
    if (ch == 0) {
        #pragma unroll
        for (int i = 0; i < QPW; ++i) {
            const int q = q0 + i;
            const float nx = nb[3 * q], ny = nb[3 * q + 1], nz = nb[3 * q + 2];
            const float ok = 0.5f *
                (unit_absdot4(ob, jo0[i], qo[i].x, qo[i].y, qo[i].z, nx, ny, nz) +
                 unit_absdot4(ob, jo1[i], qo[i].x, qo[i].y, qo[i].z, nx, ny, nz));
            const float ax = nb[3 * jm[i]], ay = nb[3 * jm[i] + 1], az = nb[3 * jm[i] + 2];
            const float ak = 0.5f *
                (unit_absdot4(ab, ja0[i], qa[i].x, qa[i].y, qa[i].z, ax, ay, az) +
                 unit_absdot4(ab, ja1[i], qa[i].x, qa[i].y, qa[i].z, ax, ay, az));
            const float d = ak - ok;
            val += d * d;
        }
    }

    __shared__ float sval[WPB];
    if (ch == 0) sval[qs] = val;
    __syncthreads();
    if (tid == 0) {
        const float s = sval[0] + sval[1] + sval[2] + sval[3];
        if (use_partial) partial[blockIdx.x] = s;
        else             atomicAdd(out, s * (1.0f / (float)(BB * NN)));
    }
}

__global__ __launch_bounds__(256) void reduce_kernel(
    const float* __restrict__ partial, float* __restrict__ out)
{
    const int tid = threadIdx.x;
    float s = 0.0f;
    #pragma unroll
    for (int i = tid; i < NBLK; i += 256) s += partial[i];
    #pragma unroll
    for (int off = 32; off > 0; off >>= 1) s += __shfl_down(s, off);
    __shared__ float ls[4];
    if ((tid & 63) == 0) ls[tid >> 6] = s;
    __syncthreads();
    if (tid == 0)
        out[0] = (ls[0] + ls[1] + ls[2] + ls[3]) * (1.0f / (float)(BB * NN));
}

extern "C" void kernel_launch(void* const* d_in, const int* in_sizes, int n_in,
                              void* d_out, int out_size, void* d_ws, size_t ws_size,
                              hipStream_t stream) {
    const float* ori = (const float*)d_in[0];
    const float* adv = (const float*)d_in[1];
    const float* nrm = (const float*)d_in[2];
    float* out = (float*)d_out;

    float4* oriP = (float4*)d_ws;                    // 256 KB
    float4* advP = oriP + (size_t)BB * NN;           // 256 KB
    float*  part = (float*)(advP + (size_t)BB * NN); // 4 KB
    const size_t need = (size_t)2 * BB * NN * sizeof(float4) + NBLK * sizeof(float);
    const int use_partial = (ws_size >= need) ? 1 : 0;

    if (!use_partial)
        hipMemsetAsync(out, 0, sizeof(float), stream);

    hipLaunchKernelGGL(pack_kernel, dim3((BB * NN + 255) / 256), dim3(256), 0, stream,
                       ori, adv, oriP, advP);
    hipLaunchKernelGGL(knn_kernel, dim3(NBLK), dim3(256), 0, stream,
                       oriP, advP, nrm, part, out, use_partial);
    if (use_partial)
        hipLaunchKernelGGL(reduce_kernel, dim3(1), dim3(256), 0, stream, part, out);
}

// Round 6
// 104.426 us; speedup vs baseline: 1.1012x; 1.1012x over previous
//
#include <hip/hip_runtime.h>

// CurvatureLoss: B=4, N=4096, fp32.
// R6: R5 (QPW=4) regressed -> revert to R4 operating point (QPW=2, 8192
// waves = 8/SIMD; that TLP is needed since real VALU throughput ~65% of
// ideal). Cut per-step ops ~50 -> ~42:
//  - no per-step self-exclusion: self key q.q-0.5|q|^2 is guaranteed global
//    rank-1 (gap ~1e-3 >> ulp). Track top-3 in-loop (v_med3_f32, 3 ops,
//    ILP-flat), collapse self lane once post-loop, then cheap top-2 merge.
//  - embed written as (t & mask) | eb -> single v_and_or_b32.
// Everything else identical to R4 (coalesced 16B/lane loads, butterfly
// __shfl_xor merge, ballot index recovery, partial+reduce epilogue).

constexpr int BB   = 4;
constexpr int NN   = 4096;
constexpr int QPB  = 8;              // queries per block (4 waves x 2)
constexpr int CPB  = 64;             // chunk = lane
constexpr int NK   = NN / CPB;       // 64 steps; candidate j = 64*k + lane
constexpr int NBLK = BB * NN / QPB;  // 2048 blocks
constexpr float NEGBIG = -3.402823466e+38f;

__global__ __launch_bounds__(256) void pack_kernel(
    const float* __restrict__ ori, const float* __restrict__ adv,
    float4* __restrict__ oriP, float4* __restrict__ advP)
{
    const int i = blockIdx.x * blockDim.x + threadIdx.x;
    if (i < BB * NN) {
        float x = ori[3 * i], y = ori[3 * i + 1], z = ori[3 * i + 2];
        oriP[i] = make_float4(x, y, z, 0.5f * (x * x + y * y + z * z));
        x = adv[3 * i]; y = adv[3 * i + 1]; z = adv[3 * i + 2];
        advP[i] = make_float4(x, y, z, 0.5f * (x * x + y * y + z * z));
    }
}

__device__ __forceinline__ float embed6(float t, unsigned eb) {
    return __uint_as_float((__float_as_uint(t) & 0xFFFFFFC0u) | eb);  // v_and_or_b32
}

__device__ __forceinline__ float fmed3(float a, float b, float c) {
    return __builtin_amdgcn_fmed3f(a, b, c);
}

// v: merged key; p0/p1: this lane's (post-collapse) partials. Wave-uniform.
// Lowest matching lane = smallest global index (j = 64k + lane).
__device__ __forceinline__ int recover_j(float v, float p0, float p1) {
    unsigned long long m = __ballot((p0 == v) || (p1 == v));
    const int lane = (int)__ffsll(m) - 1;
    const int k = (NK - 1) - (int)(__float_as_uint(v) & (unsigned)(NK - 1));
    return (k << 6) | lane;
}

__device__ __forceinline__ float unit_absdot4(const float4* __restrict__ pc, int i,
                                              float px, float py, float pz,
                                              float nx, float ny, float nz) {
    const float4 c = pc[i];
    const float vx = c.x - px, vy = c.y - py, vz = c.z - pz;
    const float s  = vx * vx + vy * vy + vz * vz + 1e-12f;
    return fabsf((vx * nx + vy * ny + vz * nz) * (1.0f / sqrtf(s)));
}

__global__ __launch_bounds__(256, 8) void knn_kernel(
    const float4* __restrict__ oriP, const float4* __restrict__ advP,
    const float* __restrict__ nrm, float* __restrict__ partial,
    float* __restrict__ out, int use_partial)
{
    const int tid = threadIdx.x;
    const int ch  = tid & 63;          // chunk = lane
    const int qs  = tid >> 6;          // wave id 0..3
    const int b   = blockIdx.x >> 9;   // / (N/QPB = 512)
    const int qt  = blockIdx.x & 511;
    const int q0  = qt * QPB + qs * 2;
    const int q1  = q0 + 1;

    const float4* __restrict__ ob = oriP + (size_t)b * NN;
    const float4* __restrict__ ab = advP + (size_t)b * NN;
    const float*  __restrict__ nb = nrm  + (size_t)b * NN * 3;

    const float4 qo0 = ob[q0], qo1 = ob[q1];
    const float4 qa0 = ab[q0], qa1 = ab[q1];

    // top-3 trackers (max = closest); self key is guaranteed rank-1.
    float oA0 = NEGBIG, oB0 = NEGBIG, oC0 = NEGBIG;   // q0 ori-ori
    float oA1 = NEGBIG, oB1 = NEGBIG, oC1 = NEGBIG;   // q1 ori-ori
    float aA0 = NEGBIG, aB0 = NEGBIG, aC0 = NEGBIG;   // q0 adv-adv
    float aA1 = NEGBIG, aB1 = NEGBIG, aC1 = NEGBIG;   // q1 adv-adv
    float m0  = NEGBIG, m1  = NEGBIG;                 // adv->ori argmax

    const float4* __restrict__ op = ob + ch;
    const float4* __restrict__ ap = ab + ch;

    #pragma unroll 4
    for (int k = 0; k < NK; ++k) {
        const float4 co = op[k * CPB];
        const float4 ca = ap[k * CPB];
        const unsigned eb = (unsigned)(NK - 1 - k);  // smaller index -> larger key

        float t;
        t = fmaf(qo0.z, co.z, -co.w); t = fmaf(qo0.y, co.y, t); t = fmaf(qo0.x, co.x, t);
        const float ko0 = embed6(t, eb);
        t = fmaf(qo1.z, co.z, -co.w); t = fmaf(qo1.y, co.y, t); t = fmaf(qo1.x, co.x, t);
        const float ko1 = embed6(t, eb);
        t = fmaf(qa0.z, co.z, -co.w); t = fmaf(qa0.y, co.y, t); t = fmaf(qa0.x, co.x, t);
        const float km0 = embed6(t, eb);
        t = fmaf(qa1.z, co.z, -co.w); t = fmaf(qa1.y, co.y, t); t = fmaf(qa1.x, co.x, t);
        const float km1 = embed6(t, eb);
        t = fmaf(qa0.z, ca.z, -ca.w); t = fmaf(qa0.y, ca.y, t); t = fmaf(qa0.x, ca.x, t);
        const float ka0 = embed6(t, eb);
        t = fmaf(qa1.z, ca.z, -ca.w); t = fmaf(qa1.y, ca.y, t); t = fmaf(qa1.x, ca.x, t);
        const float ka1 = embed6(t, eb);

        // top-3 update, all from OLD values (3-wide ILP):
        oC0 = fmed3(oB0, oC0, ko0); oB0 = fmed3(oA0, oB0, ko0); oA0 = fmaxf(oA0, ko0);
        oC1 = fmed3(oB1, oC1, ko1); oB1 = fmed3(oA1, oB1, ko1); oA1 = fmaxf(oA1, ko1);
        aC0 = fmed3(aB0, aC0, ka0); aB0 = fmed3(aA0, aB0, ka0); aA0 = fmaxf(aA0, ka0);
        aC1 = fmed3(aB1, aC1, ka1); aB1 = fmed3(aA1, aB1, ka1); aA1 = fmaxf(aA1, ka1);
        m0  = fmaxf(m0, km0);
        m1  = fmaxf(m1, km1);
    }

    // collapse self (guaranteed lane rank-1 in the self lane): drop it, keep 2.
    const bool s0 = ((q0 & 63) == ch);
    const bool s1 = ((q1 & 63) == ch);
    oA0 = s0 ? oB0 : oA0;  oB0 = s0 ? oC0 : oB0;
    aA0 = s0 ? aB0 : aA0;  aB0 = s0 ? aC0 : aB0;
    oA1 = s1 ? oB1 : oA1;  oB1 = s1 ? oC1 : oB1;
    aA1 = s1 ? aB1 : aA1;  aB1 = s1 ? aC1 : aB1;

    // save per-lane partials for index recovery
    const float soA0 = oA0, soB0 = oB0, soA1 = oA1, soB1 = oB1;
    const float saA0 = aA0, saB0 = aB0, saA1 = aA1, saB1 = aB1;
    const float sm0 = m0, sm1 = m1;

    // wave butterfly top-2 merge: m0=max(a0,b0); m1=max(min(a0,b0),max(a1,b1))
    #pragma unroll
    for (int off = 1; off < 64; off <<= 1) {
        float r0, r1, mn;
        r0 = __shfl_xor(oA0, off); r1 = __shfl_xor(oB0, off);
        mn = fminf(oA0, r0); oA0 = fmaxf(oA0, r0); oB0 = fmaxf(mn, fmaxf(oB0, r1));
        r0 = __shfl_xor(oA1, off); r1 = __shfl_xor(oB1, off);
        mn = fminf(oA1, r0); oA1 = fmaxf(oA1, r0); oB1 = fmaxf(mn, fmaxf(oB1, r1));
        r0 = __shfl_xor(aA0, off); r1 = __shfl_xor(aB0, off);
        mn = fminf(aA0, r0); aA0 = fmaxf(aA0, r0); aB0 = fmaxf(mn, fmaxf(aB0, r1));
        r0 = __shfl_xor(aA1, off); r1 = __shfl_xor(aB1, off);
        mn = fminf(aA1, r0); aA1 = fmaxf(aA1, r0); aB1 = fmaxf(mn, fmaxf(aB1, r1));
        m0 = fmaxf(m0, __shfl_xor(m0, off));
        m1 = fmaxf(m1, __shfl_xor(m1, off));
    }

    // recover global candidate indices (wave-uniform)
    const int jo0_0 = recover_j(oA0, soA0, soB0);
    const int jo1_0 = recover_j(oB0, soA0, soB0);
    const int jo0_1 = recover_j(oA1, soA1, soB1);
    const int jo1_1 = recover_j(oB1, soA1, soB1);
    const int ja0_0 = recover_j(aA0, saA0, saB0);
    const int ja1_0 = recover_j(aB0, saA0, saB0);
    const int ja0_1 = recover_j(aA1, saA1, saB1);
    const int ja1_1 = recover_j(aB1, saA1, saB1);
    const int jm_0  = recover_j(m0, sm0, sm0);
    const int jm_1  = recover_j(m1, sm1, sm1);

    float val = 0.0f;
    if (ch < 2) {                       // lane0 -> q0, lane1 -> q1
        const int    q  = ch ? q1 : q0;
        const float4 qo = ch ? qo1 : qo0;
        const float4 qa = ch ? qa1 : qa0;
        const int io0 = ch ? jo0_1 : jo0_0;
        const int io1 = ch ? jo1_1 : jo1_0;
        const int ia0 = ch ? ja0_1 : ja0_0;
        const int ia1 = ch ? ja1_1 : ja1_0;
        const int im  = ch ? jm_1  : jm_0;

        const float nx = nb[3 * q], ny = nb[3 * q + 1], nz = nb[3 * q + 2];
        const float ok = 0.5f * (unit_absdot4(ob, io0, qo.x, qo.y, qo.z, nx, ny, nz) +
                                 unit_absdot4(ob, io1, qo.x, qo.y, qo.z, nx, ny, nz));
        const float ax = nb[3 * im], ay = nb[3 * im + 1], az = nb[3 * im + 2];
        const float ak = 0.5f * (unit_absdot4(ab, ia0, qa.x, qa.y, qa.z, ax, ay, az) +
                                 unit_absdot4(ab, ia1, qa.x, qa.y, qa.z, ax, ay, az));
        const float d = ak - ok;
        val = d * d;
    }
    val += __shfl_down(val, 1);         // lane0: q0 + q1

    __shared__ float sval[4];
    if (ch == 0) sval[qs] = val;
    __syncthreads();
    if (tid == 0) {
        const float s = sval[0] + sval[1] + sval[2] + sval[3];
        if (use_partial) partial[blockIdx.x] = s;
        else             atomicAdd(out, s * (1.0f / (float)(BB * NN)));
    }
}

__global__ __launch_bounds__(256) void reduce_kernel(
    const float* __restrict__ partial, float* __restrict__ out)
{
    const int tid = threadIdx.x;
    float s = 0.0f;
    #pragma unroll
    for (int i = tid; i < NBLK; i += 256) s += partial[i];
    #pragma unroll
    for (int off = 32; off > 0; off >>= 1) s += __shfl_down(s, off);
    __shared__ float ls[4];
    if ((tid & 63) == 0) ls[tid >> 6] = s;
    __syncthreads();
    if (tid == 0)
        out[0] = (ls[0] + ls[1] + ls[2] + ls[3]) * (1.0f / (float)(BB * NN));
}

extern "C" void kernel_launch(void* const* d_in, const int* in_sizes, int n_in,
                              void* d_out, int out_size, void* d_ws, size_t ws_size,
                              hipStream_t stream) {
    const float* ori = (const float*)d_in[0];
    const float* adv = (const float*)d_in[1];
    const float* nrm = (const float*)d_in[2];
    float* out = (float*)d_out;

    float4* oriP = (float4*)d_ws;                    // 256 KB
    float4* advP = oriP + (size_t)BB * NN;           // 256 KB
    float*  part = (float*)(advP + (size_t)BB * NN); // 8 KB
    const size_t need = (size_t)2 * BB * NN * sizeof(float4) + NBLK * sizeof(float);
    const int use_partial = (ws_size >= need) ? 1 : 0;

    if (!use_partial)
        hipMemsetAsync(out, 0, sizeof(float), stream);

    hipLaunchKernelGGL(pack_kernel, dim3((BB * NN + 255) / 256), dim3(256), 0, stream,
                       ori, adv, oriP, advP);
    hipLaunchKernelGGL(knn_kernel, dim3(NBLK), dim3(256), 0, stream,
                       oriP, advP, nrm, part, out, use_partial);
    if (use_partial)
        hipLaunchKernelGGL(reduce_kernel, dim3(1), dim3(256), 0, stream, part, out);
}

// Round 7
// 101.725 us; speedup vs baseline: 1.1304x; 1.0265x over previous
//
#include <hip/hip_runtime.h>

// CurvatureLoss: B=4, N=4096, fp32.
// R7: R6's -12% inst gave only -3.5% time -> not issue-bound; VGPR=28 shows
// zero candidate prefetch depth => per-step load-latency exposure is the
// residual. Add explicit software pipeline, prefetch distance 2 (rotated
// register buffers, unroll 2, last 2 steps peeled). Loop body identical to
// R6 (top-3 med3 trackers, 6-bit index embed, butterfly merge, ballot
// recovery, partial+reduce epilogue).

constexpr int BB   = 4;
constexpr int NN   = 4096;
constexpr int QPB  = 8;              // queries per block (4 waves x 2)
constexpr int CPB  = 64;             // chunk = lane
constexpr int NK   = NN / CPB;       // 64 steps; candidate j = 64*k + lane
constexpr int NBLK = BB * NN / QPB;  // 2048 blocks
constexpr float NEGBIG = -3.402823466e+38f;

__global__ __launch_bounds__(256) void pack_kernel(
    const float* __restrict__ ori, const float* __restrict__ adv,
    float4* __restrict__ oriP, float4* __restrict__ advP)
{
    const int i = blockIdx.x * blockDim.x + threadIdx.x;
    if (i < BB * NN) {
        float x = ori[3 * i], y = ori[3 * i + 1], z = ori[3 * i + 2];
        oriP[i] = make_float4(x, y, z, 0.5f * (x * x + y * y + z * z));
        x = adv[3 * i]; y = adv[3 * i + 1]; z = adv[3 * i + 2];
        advP[i] = make_float4(x, y, z, 0.5f * (x * x + y * y + z * z));
    }
}

__device__ __forceinline__ float embed6(float t, unsigned eb) {
    return __uint_as_float((__float_as_uint(t) & 0xFFFFFFC0u) | eb);  // v_and_or_b32
}

__device__ __forceinline__ float fmed3(float a, float b, float c) {
    return __builtin_amdgcn_fmed3f(a, b, c);
}

// v: merged key; p0/p1: this lane's (post-collapse) partials. Wave-uniform.
// Lowest matching lane = smallest global index (j = 64k + lane).
__device__ __forceinline__ int recover_j(float v, float p0, float p1) {
    unsigned long long m = __ballot((p0 == v) || (p1 == v));
    const int lane = (int)__ffsll(m) - 1;
    const int k = (NK - 1) - (int)(__float_as_uint(v) & (unsigned)(NK - 1));
    return (k << 6) | lane;
}

__device__ __forceinline__ float unit_absdot4(const float4* __restrict__ pc, int i,
                                              float px, float py, float pz,
                                              float nx, float ny, float nz) {
    const float4 c = pc[i];
    const float vx = c.x - px, vy = c.y - py, vz = c.z - pz;
    const float s  = vx * vx + vy * vy + vz * vz + 1e-12f;
    return fabsf((vx * nx + vy * ny + vz * nz) * (1.0f / sqrtf(s)));
}

__global__ __launch_bounds__(256, 8) void knn_kernel(
    const float4* __restrict__ oriP, const float4* __restrict__ advP,
    const float* __restrict__ nrm, float* __restrict__ partial,
    float* __restrict__ out, int use_partial)
{
    const int tid = threadIdx.x;
    const int ch  = tid & 63;          // chunk = lane
    const int qs  = tid >> 6;          // wave id 0..3
    const int b   = blockIdx.x >> 9;   // / (N/QPB = 512)
    const int qt  = blockIdx.x & 511;
    const int q0  = qt * QPB + qs * 2;
    const int q1  = q0 + 1;

    const float4* __restrict__ ob = oriP + (size_t)b * NN;
    const float4* __restrict__ ab = advP + (size_t)b * NN;
    const float*  __restrict__ nb = nrm  + (size_t)b * NN * 3;

    const float4 qo0 = ob[q0], qo1 = ob[q1];
    const float4 qa0 = ab[q0], qa1 = ab[q1];

    // top-3 trackers (max = closest); self key is guaranteed rank-1.
    float oA0 = NEGBIG, oB0 = NEGBIG, oC0 = NEGBIG;   // q0 ori-ori
    float oA1 = NEGBIG, oB1 = NEGBIG, oC1 = NEGBIG;   // q1 ori-ori
    float aA0 = NEGBIG, aB0 = NEGBIG, aC0 = NEGBIG;   // q0 adv-adv
    float aA1 = NEGBIG, aB1 = NEGBIG, aC1 = NEGBIG;   // q1 adv-adv
    float m0  = NEGBIG, m1  = NEGBIG;                 // adv->ori argmax

    const float4* __restrict__ op = ob + ch;
    const float4* __restrict__ ap = ab + ch;

    // one step of the key/selection body (identical math to R6)
    auto stepf = [&](const float4& co, const float4& ca, unsigned eb) {
        float t;
        t = fmaf(qo0.z, co.z, -co.w); t = fmaf(qo0.y, co.y, t); t = fmaf(qo0.x, co.x, t);
        const float ko0 = embed6(t, eb);
        t = fmaf(qo1.z, co.z, -co.w); t = fmaf(qo1.y, co.y, t); t = fmaf(qo1.x, co.x, t);
        const float ko1 = embed6(t, eb);
        t = fmaf(qa0.z, co.z, -co.w); t = fmaf(qa0.y, co.y, t); t = fmaf(qa0.x, co.x, t);
        const float km0 = embed6(t, eb);
        t = fmaf(qa1.z, co.z, -co.w); t = fmaf(qa1.y, co.y, t); t = fmaf(qa1.x, co.x, t);
        const float km1 = embed6(t, eb);
        t = fmaf(qa0.z, ca.z, -ca.w); t = fmaf(qa0.y, ca.y, t); t = fmaf(qa0.x, ca.x, t);
        const float ka0 = embed6(t, eb);
        t = fmaf(qa1.z, ca.z, -ca.w); t = fmaf(qa1.y, ca.y, t); t = fmaf(qa1.x, ca.x, t);
        const float ka1 = embed6(t, eb);

        // top-3 update, all from OLD values (3-wide ILP):
        oC0 = fmed3(oB0, oC0, ko0); oB0 = fmed3(oA0, oB0, ko0); oA0 = fmaxf(oA0, ko0);
        oC1 = fmed3(oB1, oC1, ko1); oB1 = fmed3(oA1, oB1, ko1); oA1 = fmaxf(oA1, ko1);
        aC0 = fmed3(aB0, aC0, ka0); aB0 = fmed3(aA0, aB0, ka0); aA0 = fmaxf(aA0, ka0);
        aC1 = fmed3(aB1, aC1, ka1); aB1 = fmed3(aA1, aB1, ka1); aA1 = fmaxf(aA1, ka1);
        m0  = fmaxf(m0, km0);
        m1  = fmaxf(m1, km1);
    };

    // software pipeline, prefetch distance 2; rotations become renames
    // under unroll 2; last 2 steps peeled (no OOB prefetch).
    float4 c0o = op[0 * CPB], c0a = ap[0 * CPB];
    float4 c1o = op[1 * CPB], c1a = ap[1 * CPB];

    #pragma unroll 2
    for (int k = 0; k < NK - 2; ++k) {
        const float4 c2o = op[(k + 2) * CPB];
        const float4 c2a = ap[(k + 2) * CPB];
        stepf(c0o, c0a, (unsigned)(NK - 1 - k));
        c0o = c1o; c0a = c1a;
        c1o = c2o; c1a = c2a;
    }
    stepf(c0o, c0a, 1u);
    stepf(c1o, c1a, 0u);

    // collapse self (guaranteed lane rank-1 in the self lane): drop it, keep 2.
    const bool s0 = ((q0 & 63) == ch);
    const bool s1 = ((q1 & 63) == ch);
    oA0 = s0 ? oB0 : oA0;  oB0 = s0 ? oC0 : oB0;
    aA0 = s0 ? aB0 : aA0;  aB0 = s0 ? aC0 : aB0;
    oA1 = s1 ? oB1 : oA1;  oB1 = s1 ? oC1 : oB1;
    aA1 = s1 ? aB1 : aA1;  aB1 = s1 ? aC1 : aB1;

    // save per-lane partials for index recovery
    const float soA0 = oA0, soB0 = oB0, soA1 = oA1, soB1 = oB1;
    const float saA0 = aA0, saB0 = aB0, saA1 = aA1, saB1 = aB1;
    const float sm0 = m0, sm1 = m1;

    // wave butterfly top-2 merge: m0=max(a0,b0); m1=max(min(a0,b0),max(a1,b1))
    #pragma unroll
    for (int off = 1; off < 64; off <<= 1) {
        float r0, r1, mn;
        r0 = __shfl_xor(oA0, off); r1 = __shfl_xor(oB0, off);
        mn = fminf(oA0, r0); oA0 = fmaxf(oA0, r0); oB0 = fmaxf(mn, fmaxf(oB0, r1));
        r0 = __shfl_xor(oA1, off); r1 = __shfl_xor(oB1, off);
        mn = fminf(oA1, r0); oA1 = fmaxf(oA1, r0); oB1 = fmaxf(mn, fmaxf(oB1, r1));
        r0 = __shfl_xor(aA0, off); r1 = __shfl_xor(aB0, off);
        mn = fminf(aA0, r0); aA0 = fmaxf(aA0, r0); aB0 = fmaxf(mn, fmaxf(aB0, r1));
        r0 = __shfl_xor(aA1, off); r1 = __shfl_xor(aB1, off);
        mn = fminf(aA1, r0); aA1 = fmaxf(aA1, r0); aB1 = fmaxf(mn, fmaxf(aB1, r1));
        m0 = fmaxf(m0, __shfl_xor(m0, off));
        m1 = fmaxf(m1, __shfl_xor(m1, off));
    }

    // recover global candidate indices (wave-uniform)
    const int jo0_0 = recover_j(oA0, soA0, soB0);
    const int jo1_0 = recover_j(oB0, soA0, soB0);
    const int jo0_1 = recover_j(oA1, soA1, soB1);
    const int jo1_1 = recover_j(oB1, soA1, soB1);
    const int ja0_0 = recover_j(aA0, saA0, saB0);
    const int ja1_0 = recover_j(aB0, saA0, saB0);
    const int ja0_1 = recover_j(aA1, saA1, saB1);
    const int ja1_1 = recover_j(aB1, saA1, saB1);
    const int jm_0  = recover_j(m0, sm0, sm0);
    const int jm_1  = recover_j(m1, sm1, sm1);

    float val = 0.0f;
    if (ch < 2) {                       // lane0 -> q0, lane1 -> q1
        const int    q  = ch ? q1 : q0;
        const float4 qo = ch ? qo1 : qo0;
        const float4 qa = ch ? qa1 : qa0;
        const int io0 = ch ? jo0_1 : jo0_0;
        const int io1 = ch ? jo1_1 : jo1_0;
        const int ia0 = ch ? ja0_1 : ja0_0;
        const int ia1 = ch ? ja1_1 : ja1_0;
        const int im  = ch ? jm_1  : jm_0;

        const float nx = nb[3 * q], ny = nb[3 * q + 1], nz = nb[3 * q + 2];
        const float ok = 0.5f * (unit_absdot4(ob, io0, qo.x, qo.y, qo.z, nx, ny, nz) +
                                 unit_absdot4(ob, io1, qo.x, qo.y, qo.z, nx, ny, nz));
        const float ax = nb[3 * im], ay = nb[3 * im + 1], az = nb[3 * im + 2];
        const float ak = 0.5f * (unit_absdot4(ab, ia0, qa.x, qa.y, qa.z, ax, ay, az) +
                                 unit_absdot4(ab, ia1, qa.x, qa.y, qa.z, ax, ay, az));
        const float d = ak - ok;
        val = d * d;
    }
    val += __shfl_down(val, 1);         // lane0: q0 + q1

    __shared__ float sval[4];
    if (ch == 0) sval[qs] = val;
    __syncthreads();
    if (tid == 0) {
        const float s = sval[0] + sval[1] + sval[2] + sval[3];
        if (use_partial) partial[blockIdx.x] = s;
        else             atomicAdd(out, s * (1.0f / (float)(BB * NN)));
    }
}

__global__ __launch_bounds__(256) void reduce_kernel(
    const float* __restrict__ partial, float* __restrict__ out)
{
    const int tid = threadIdx.x;
    float s = 0.0f;
    #pragma unroll
    for (int i = tid; i < NBLK; i += 256) s += partial[i];
    #pragma unroll
    for (int off = 32; off > 0; off >>= 1) s += __shfl_down(s, off);
    __shared__ float ls[4];
    if ((tid & 63) == 0) ls[tid >> 6] = s;
    __syncthreads();
    if (tid == 0)
        out[0] = (ls[0] + ls[1] + ls[2] + ls[3]) * (1.0f / (float)(BB * NN));
}

extern "C" void kernel_launch(void* const* d_in, const int* in_sizes, int n_in,
                              void* d_out, int out_size, void* d_ws, size_t ws_size,
                              hipStream_t stream) {
    const float* ori = (const float*)d_in[0];
    const float* adv = (const float*)d_in[1];
    const float* nrm = (const float*)d_in[2];
    float* out = (float*)d_out;

    float4* oriP = (float4*)d_ws;                    // 256 KB
    float4* advP = oriP + (size_t)BB * NN;           // 256 KB
    float*  part = (float*)(advP + (size_t)BB * NN); // 8 KB
    const size_t need = (size_t)2 * BB * NN * sizeof(float4) + NBLK * sizeof(float);
    const int use_partial = (ws_size >= need) ? 1 : 0;

    if (!use_partial)
        hipMemsetAsync(out, 0, sizeof(float), stream);

    hipLaunchKernelGGL(pack_kernel, dim3((BB * NN + 255) / 256), dim3(256), 0, stream,
                       ori, adv, oriP, advP);
    hipLaunchKernelGGL(knn_kernel, dim3(NBLK), dim3(256), 0, stream,
                       oriP, advP, nrm, part, out, use_partial);
    if (use_partial)
        hipLaunchKernelGGL(reduce_kernel, dim3(1), dim3(256), 0, stream, part, out);
}